// Round 20
// baseline (49.763 us; speedup 1.0000x reference)
//
#include <hip/hip_runtime.h>

// Fully-fused cascaded-biquad IIR (DF2T) via linear state-space chunking.
// R20 = R18 skeleton + HT1-PERSISTED-IN-LDS replay:
//   - scan = R15-verified shfl form (in-wave Kogge-Stone + Bnd fold +
//     binary-bit M^lane apply); its only LDS is Msf(8x64)+Bnd(8x8) = 2.3KB
//     placed in wave 0's arena region -> waves 1..7's HT1 data SURVIVES.
//   - P1 captures u_mid (state after 32 steps, zero-init; +8 VGPR).
//   - P4 waves 1..7: s32 = u_mid + A^32*s_init (exact, linearity); compute
//     HT1 from the preserved LDS (no stage, no vmcnt), store; then stage
//     and compute HT0. Wave 0: classic R18 restage path (its region held
//     Msf/Bnd). Wave-uniform divergence only.
// LDS exactly 65536 (2-blocks/CU cliff). No register-retention of x
// (R19: VGPR 100 -> occupancy 39->20%, net loss).

namespace {
constexpr int NS     = 4;
constexpr int BATCH  = 512;
constexpr int TLEN   = 32768;      // 2^15
constexpr int NSTATE = 8;
constexpr int P      = 512;        // chunks per batch = threads per block
constexpr int L      = TLEN / P;   // 64 steps per chunk
constexpr int LQ     = L / 4;      // 16 float4 per chunk
constexpr int NSQ    = 12;         // squarings: A^2 .. A^4096
// Msf rows: 0=A^32, 1=A^64, 2=A^128, 3=A^256, 4=A^512, 5=A^1024,
//           6=A^2048, 7=A^4096.  (M = A^64; scan level d uses row d+1,
//           cross-wave fold uses row 7, s32 correction uses row 0.)
}

#if defined(__has_builtin)
#  if __has_builtin(__builtin_amdgcn_global_load_lds)
#    define USE_GLL 1
#  endif
#endif
#ifndef USE_GLL
#  define USE_GLL 0
#endif

#define WAIT_VM0 do { asm volatile("s_waitcnt vmcnt(0)" ::: "memory"); \
                      __builtin_amdgcn_sched_barrier(0); } while (0)
#define WAIT_LGKM0 do { asm volatile("s_waitcnt lgkmcnt(0)" ::: "memory"); \
                        __builtin_amdgcn_sched_barrier(0); } while (0)

__device__ __forceinline__ void load_coefs(const float* __restrict__ bc,
                                           const float* __restrict__ ac,
                                           float b0[NS], float b1[NS], float b2[NS],
                                           float a1[NS], float a2[NS]) {
#pragma unroll
  for (int k = 0; k < NS; ++k) {
    b0[k] = bc[3 * k];
    b1[k] = bc[3 * k + 1];
    b2[k] = bc[3 * k + 2];
    a1[k] = ac[2 * k];
    a2[k] = ac[2 * k + 1];
  }
}

// One time-step through the 4-section cascade (matches reference exactly).
__device__ __forceinline__ float step_cascade(float sig,
                                              const float b0[NS], const float b1[NS],
                                              const float b2[NS], const float a1[NS],
                                              const float a2[NS],
                                              float s1[NS], float s2[NS]) {
#pragma unroll
  for (int k = 0; k < NS; ++k) {
    float y = fmaf(b0[k], sig, s1[k]);
    s1[k]   = fmaf(-a1[k], y, fmaf(b1[k], sig, s2[k]));
    s2[k]   = fmaf(-a2[k], y, b2[k] * sig);
    sig = y;
  }
  return sig;
}

#define CO b0, b1, b2, a1, a2

__device__ __forceinline__ void adv4(const float4 u,
                                     const float b0[NS], const float b1[NS],
                                     const float b2[NS], const float a1[NS],
                                     const float a2[NS], float s1[NS], float s2[NS]) {
  (void)step_cascade(u.x, CO, s1, s2);
  (void)step_cascade(u.y, CO, s1, s2);
  (void)step_cascade(u.z, CO, s1, s2);
  (void)step_cascade(u.w, CO, s1, s2);
}

__device__ __forceinline__ float4 out4(const float4 u,
                                       const float b0[NS], const float b1[NS],
                                       const float b2[NS], const float a1[NS],
                                       const float a2[NS], float s1[NS], float s2[NS]) {
  float4 y;
  y.x = step_cascade(u.x, CO, s1, s2);
  y.y = step_cascade(u.y, CO, s1, s2);
  y.z = step_cascade(u.z, CO, s1, s2);
  y.w = step_cascade(u.w, CO, s1, s2);
  return y;
}

// Stage one half-tile (64 chunks x 8 f4 = 8KB): linear LDS dest, per-lane
// pre-swizzled global source (R12/R13-validated). Dense 128B lines.
__device__ __forceinline__ void stage_ht(const float4* __restrict__ gx_w,
                                         float4* R, int lane, int ht) {
#if USE_GLL
#pragma unroll
  for (int j = 0; j < 8; ++j) {
    const int cc = j * 8 + (lane >> 3);
    const int qq = lane & 7;
    const float4* g = gx_w + cc * 16 + ht * 8 + (qq ^ (cc & 7));
    __builtin_amdgcn_global_load_lds(
        (const __attribute__((address_space(1))) void*)g,
        (__attribute__((address_space(3))) void*)&R[j * 64], 16, 0, 0);
  }
#else
#pragma unroll
  for (int j = 0; j < 8; ++j) {
    const int cc = j * 8 + (lane >> 3);
    const int qq = lane & 7;
    R[j * 64 + lane] = gx_w[cc * 16 + ht * 8 + (qq ^ (cc & 7))];
  }
#endif
}

__global__ __launch_bounds__(P) void k_fused(const float* __restrict__ x,
                                             const float* __restrict__ bc,
                                             const float* __restrict__ ac,
                                             float* __restrict__ out) {
  // 64 KiB arena. Wave wv owns f4 [wv*512, +512). During the scan window
  // wave 0's first 2304B hold Msf (8x64 floats) + Bndf (64 floats).
  __shared__ float4 arena[4096];
  float* Msf  = reinterpret_cast<float*>(arena);        // floats [0,512)
  float* Bndf = reinterpret_cast<float*>(arena) + 512;  // floats [512,576)

  const int t    = threadIdx.x;
  const int lane = t & 63;
  const int wv   = t >> 6;
  const int swz  = lane & 7;
  float4* __restrict__ R = arena + (wv << 9);

  float b0[NS], b1[NS], b2[NS], a1[NS], a2[NS];
  load_coefs(bc, ac, b0, b1, b2, a1, a2);

  const float4* __restrict__ gx_w = reinterpret_cast<const float4*>(x) +
      (size_t)blockIdx.x * (P * LQ) + ((size_t)wv << 10);
  float4* __restrict__ gy_w = reinterpret_cast<float4*>(out) +
      (size_t)blockIdx.x * (P * LQ) + ((size_t)wv << 10);

  // ---- P1 HT0 staging (HBM latency hides under Ms squarings) ----
  stage_ht(gx_w, R, lane, 0);

  // ---- Ms squarings in-register (wave 0 only), stored AFTER P1 barrier ----
  float mpow[8];
#pragma unroll
  for (int i = 0; i < 8; ++i) mpow[i] = 0.0f;
  if (t < 64) {
    const int r = lane >> 3, c = lane & 7;
    float p1[NS] = {0.f, 0.f, 0.f, 0.f};
    float p2[NS] = {0.f, 0.f, 0.f, 0.f};
    if (c & 1) p2[c >> 1] = 1.0f; else p1[c >> 1] = 1.0f;
    (void)step_cascade(0.0f, CO, p1, p2);
    float m = (r & 1) ? p2[r >> 1] : p1[r >> 1];  // A element (r,c)
#pragma unroll
    for (int it = 0; it < NSQ; ++it) {            // after it: m = A^(2^(it+1))
      float acc = 0.0f;
#pragma unroll
      for (int k = 0; k < NSTATE; ++k)
        acc = fmaf(__shfl(m, r * 8 + k), __shfl(m, k * 8 + c), acc);
      m = acc;
      if (it >= 4) mpow[it - 4] = m;              // A^32 .. A^4096
    }
  }

  // ---- P1: chunk state from zero; capture u_mid after HT0 ----
  float s1[NS] = {0.f, 0.f, 0.f, 0.f};
  float s2[NS] = {0.f, 0.f, 0.f, 0.f};
  WAIT_VM0;
#pragma unroll
  for (int q = 0; q < 8; ++q) adv4(R[lane * 8 + (q ^ swz)], CO, s1, s2);
  float um[NSTATE];
#pragma unroll
  for (int k = 0; k < NS; ++k) { um[2 * k] = s1[k]; um[2 * k + 1] = s2[k]; }
  WAIT_LGKM0;  // WAR: HT0 ds_reads retired before HT1 overwrites
  stage_ht(gx_w, R, lane, 1);
  WAIT_VM0;
#pragma unroll
  for (int q = 0; q < 8; ++q) adv4(R[lane * 8 + (q ^ swz)], CO, s1, s2);

  float w[NSTATE];
#pragma unroll
  for (int k = 0; k < NS; ++k) { w[2 * k] = s1[k]; w[2 * k + 1] = s2[k]; }

  __syncthreads();  // #1: all P1 LDS reads done (HT1 data stays resident!)
  if (t < 64) {
#pragma unroll
    for (int i = 0; i < 8; ++i) Msf[i * 64 + t] = mpow[i];
  }
  __syncthreads();  // #2: Msf visible to all waves

  // ---- scan levels 0..5: in-wave Kogge-Stone via __shfl ----
#pragma unroll
  for (int d = 0; d < 6; ++d) {
    const int off = 1 << d;
    const int src = (lane >= off) ? (lane - off) : lane;
    float prev[NSTATE];
#pragma unroll
    for (int r = 0; r < NSTATE; ++r) prev[r] = __shfl(w[r], src);
    if (lane >= off) {
#pragma unroll
      for (int r = 0; r < NSTATE; ++r) {
        float acc = w[r];
#pragma unroll
        for (int k = 0; k < NSTATE; ++k)
          acc = fmaf(Msf[(d + 1) * 64 + r * 8 + k], prev[k], acc);  // M^(2^d)
        w[r] = acc;
      }
    }
  }

  // ---- Bnd exchange ----
  if (lane == 63) {
#pragma unroll
    for (int r = 0; r < NSTATE; ++r) Bndf[wv * 8 + r] = w[r];
  }
  __syncthreads();  // #3

  // ---- cross-wave prefix: fold Bnd[0..wv-1] through M^64 = A^4096 (row 7) ----
  float Pv[NSTATE] = {0.f, 0.f, 0.f, 0.f, 0.f, 0.f, 0.f, 0.f};
  for (int j = 0; j < wv; ++j) {  // wave-uniform trip count
    float np[NSTATE];
#pragma unroll
    for (int r = 0; r < NSTATE; ++r) {
      float acc = Bndf[j * 8 + r];
#pragma unroll
      for (int k = 0; k < NSTATE; ++k)
        acc = fmaf(Msf[7 * 64 + r * 8 + k], Pv[k], acc);
      np[r] = acc;
    }
#pragma unroll
    for (int r = 0; r < NSTATE; ++r) Pv[r] = np[r];
  }

  // ---- z = M^lane * P (binary bits, rows 1..6); s_init = u_excl + z ----
  float z[NSTATE];
#pragma unroll
  for (int r = 0; r < NSTATE; ++r) z[r] = Pv[r];
#pragma unroll
  for (int b = 0; b < 6; ++b) {
    float zb[NSTATE];
#pragma unroll
    for (int r = 0; r < NSTATE; ++r) {
      float acc = 0.0f;
#pragma unroll
      for (int k = 0; k < NSTATE; ++k)
        acc = fmaf(Msf[(b + 1) * 64 + r * 8 + k], z[k], acc);
      zb[r] = acc;
    }
    const bool bit = (lane >> b) & 1;
#pragma unroll
    for (int r = 0; r < NSTATE; ++r) z[r] = bit ? zb[r] : z[r];
  }
  float si[NSTATE];  // exact chunk-initial state
  {
    const int esrc = lane ? lane - 1 : 0;
#pragma unroll
    for (int r = 0; r < NSTATE; ++r) {
      const float ue = __shfl(w[r], esrc);
      si[r] = (lane ? ue : 0.0f) + z[r];
    }
  }

  // ---- s32 = u_mid + A^32 * s_init (exact state at step 32; row 0) ----
  float sm[NSTATE];
#pragma unroll
  for (int r = 0; r < NSTATE; ++r) {
    float acc = um[r];
#pragma unroll
    for (int k = 0; k < NSTATE; ++k)
      acc = fmaf(Msf[0 * 64 + r * 8 + k], si[k], acc);
    sm[r] = acc;
  }

  __syncthreads();  // #4: all Msf/Bnd reads done; wave 0's region reusable

  if (wv != 0) {
    // ---- waves 1..7: HT1 from PRESERVED LDS (no stage, no vmcnt) ----
#pragma unroll
    for (int k = 0; k < NS; ++k) { s1[k] = sm[2 * k]; s2[k] = sm[2 * k + 1]; }
#pragma unroll
    for (int q = 0; q < 8; ++q) {
      const int s = lane * 8 + (q ^ swz);
      R[s] = out4(R[s], CO, s1, s2);  // in-place: own slots only
    }
    WAIT_LGKM0;
#pragma unroll
    for (int j = 0; j < 8; ++j) {
      const int cc = j * 8 + (lane >> 3);
      const int qq = lane & 7;
      gy_w[cc * 16 + 8 + (qq ^ (cc & 7))] = R[j * 64 + lane];  // ht=1 out
    }
    WAIT_LGKM0;  // transpose reads done before HT0 staging overwrites
    // ---- then stage + compute HT0 from s_init ----
    stage_ht(gx_w, R, lane, 0);
#pragma unroll
    for (int k = 0; k < NS; ++k) { s1[k] = si[2 * k]; s2[k] = si[2 * k + 1]; }
    WAIT_VM0;
#pragma unroll
    for (int q = 0; q < 8; ++q) {
      const int s = lane * 8 + (q ^ swz);
      R[s] = out4(R[s], CO, s1, s2);
    }
    WAIT_LGKM0;
#pragma unroll
    for (int j = 0; j < 8; ++j) {
      const int cc = j * 8 + (lane >> 3);
      const int qq = lane & 7;
      gy_w[cc * 16 + (qq ^ (cc & 7))] = R[j * 64 + lane];  // ht=0 out
    }
  } else {
    // ---- wave 0: classic restage path (its region held Msf/Bnd) ----
#pragma unroll
    for (int k = 0; k < NS; ++k) { s1[k] = si[2 * k]; s2[k] = si[2 * k + 1]; }
#pragma unroll
    for (int ht = 0; ht < 2; ++ht) {
      stage_ht(gx_w, R, lane, ht);
      WAIT_VM0;
#pragma unroll
      for (int q = 0; q < 8; ++q) {
        const int s = lane * 8 + (q ^ swz);
        R[s] = out4(R[s], CO, s1, s2);  // state carries HT0 -> HT1
      }
      WAIT_LGKM0;
#pragma unroll
      for (int j = 0; j < 8; ++j) {
        const int cc = j * 8 + (lane >> 3);
        const int qq = lane & 7;
        gy_w[cc * 16 + ht * 8 + (qq ^ (cc & 7))] = R[j * 64 + lane];
      }
      if (ht == 0) WAIT_LGKM0;
    }
  }
}

extern "C" void kernel_launch(void* const* d_in, const int* in_sizes, int n_in,
                              void* d_out, int out_size, void* d_ws, size_t ws_size,
                              hipStream_t stream) {
  const float* x  = (const float*)d_in[0];  // (B, T, 1)
  const float* bc = (const float*)d_in[1];  // (NS, 3)
  const float* ac = (const float*)d_in[2];  // (NS, 2)
  float* out = (float*)d_out;               // (B, T, 1)

  k_fused<<<BATCH, P, 0, stream>>>(x, bc, ac, out);
}

// Round 21
// 41.433 us; speedup vs baseline: 1.2010x; 1.2010x over previous
//
#include <hip/hip_runtime.h>

// Fully-fused cascaded-biquad IIR (DF2T) via linear state-space chunking.
// CHAMPION (R18, 41.47us): R13 skeleton + shfl-scan levels 0..5 + waves
// 3..7 P4-HT0 prefetch. Locked after R14-R20 exploration established the
// two hardware cliffs that bound this structure:
//   - LDS > 65536 B  -> blocks/CU drops 2 -> 1 (R15: 67584 -> 21% occ)
//   - VGPR > ~64     -> blocks/CU drops 2 -> 1 (R19: 100, R20: 84 -> 20%)
// and that P4's x re-read cannot be eliminated within those budgets
// (register-resident x: +48 VGPR; LDS-preserved HT1: +32 VGPR; both lose
// more to residency than they save in traffic).
//   P1: gll dense 128B staging (pre-swizzled source, linear LDS dest)
//   P2: scan levels 0..5 in-wave via __shfl; 6..8 Wf-exchange
//   P3: exclusive shift -> s_init in registers
//   P4: stage -> in-place replay -> dense transpose store

namespace {
constexpr int NS     = 4;
constexpr int BATCH  = 512;
constexpr int TLEN   = 32768;      // 2^15
constexpr int NSTATE = 8;
constexpr int P      = 512;        // chunks per batch = threads per block
constexpr int L      = TLEN / P;   // 64 steps per chunk
constexpr int LQ     = L / 4;      // 16 float4 per chunk
constexpr int LOG2P  = 9;
constexpr int LOG2L  = 6;
constexpr int NSQ    = LOG2L + LOG2P - 1;  // 14 squaring iterations
}

#if defined(__has_builtin)
#  if __has_builtin(__builtin_amdgcn_global_load_lds)
#    define USE_GLL 1
#  endif
#endif
#ifndef USE_GLL
#  define USE_GLL 0
#endif

#define WAIT_VM0 do { asm volatile("s_waitcnt vmcnt(0)" ::: "memory"); \
                      __builtin_amdgcn_sched_barrier(0); } while (0)
#define WAIT_LGKM0 do { asm volatile("s_waitcnt lgkmcnt(0)" ::: "memory"); \
                        __builtin_amdgcn_sched_barrier(0); } while (0)

__device__ __forceinline__ void load_coefs(const float* __restrict__ bc,
                                           const float* __restrict__ ac,
                                           float b0[NS], float b1[NS], float b2[NS],
                                           float a1[NS], float a2[NS]) {
#pragma unroll
  for (int k = 0; k < NS; ++k) {
    b0[k] = bc[3 * k];
    b1[k] = bc[3 * k + 1];
    b2[k] = bc[3 * k + 2];
    a1[k] = ac[2 * k];
    a2[k] = ac[2 * k + 1];
  }
}

// One time-step through the 4-section cascade (matches reference exactly).
__device__ __forceinline__ float step_cascade(float sig,
                                              const float b0[NS], const float b1[NS],
                                              const float b2[NS], const float a1[NS],
                                              const float a2[NS],
                                              float s1[NS], float s2[NS]) {
#pragma unroll
  for (int k = 0; k < NS; ++k) {
    float y = fmaf(b0[k], sig, s1[k]);
    s1[k]   = fmaf(-a1[k], y, fmaf(b1[k], sig, s2[k]));
    s2[k]   = fmaf(-a2[k], y, b2[k] * sig);
    sig = y;
  }
  return sig;
}

#define CO b0, b1, b2, a1, a2

__device__ __forceinline__ void adv4(const float4 u,
                                     const float b0[NS], const float b1[NS],
                                     const float b2[NS], const float a1[NS],
                                     const float a2[NS], float s1[NS], float s2[NS]) {
  (void)step_cascade(u.x, CO, s1, s2);
  (void)step_cascade(u.y, CO, s1, s2);
  (void)step_cascade(u.z, CO, s1, s2);
  (void)step_cascade(u.w, CO, s1, s2);
}

__device__ __forceinline__ float4 out4(const float4 u,
                                       const float b0[NS], const float b1[NS],
                                       const float b2[NS], const float a1[NS],
                                       const float a2[NS], float s1[NS], float s2[NS]) {
  float4 y;
  y.x = step_cascade(u.x, CO, s1, s2);
  y.y = step_cascade(u.y, CO, s1, s2);
  y.z = step_cascade(u.z, CO, s1, s2);
  y.w = step_cascade(u.w, CO, s1, s2);
  return y;
}

// Stage one half-tile (64 chunks x 8 f4 = 8KB): linear LDS dest, per-lane
// pre-swizzled global source (R12/R13-validated). Dense 128B lines.
__device__ __forceinline__ void stage_ht(const float4* __restrict__ gx_w,
                                         float4* R, int lane, int ht) {
#if USE_GLL
#pragma unroll
  for (int j = 0; j < 8; ++j) {
    const int cc = j * 8 + (lane >> 3);
    const int qq = lane & 7;
    const float4* g = gx_w + cc * 16 + ht * 8 + (qq ^ (cc & 7));
    __builtin_amdgcn_global_load_lds(
        (const __attribute__((address_space(1))) void*)g,
        (__attribute__((address_space(3))) void*)&R[j * 64], 16, 0, 0);
  }
#else
#pragma unroll
  for (int j = 0; j < 8; ++j) {
    const int cc = j * 8 + (lane >> 3);
    const int qq = lane & 7;
    R[j * 64 + lane] = gx_w[cc * 16 + ht * 8 + (qq ^ (cc & 7))];
  }
#endif
}

__global__ __launch_bounds__(P) void k_fused(const float* __restrict__ x,
                                             const float* __restrict__ bc,
                                             const float* __restrict__ ac,
                                             float* __restrict__ out) {
  // 64 KiB arena. P1/P4: wave wv owns f4 [wv*512, wv*512+512).
  // Scan: Msf = floats [0,576), Wf = floats [576,5184) -- covers only
  // waves 0..2's regions; waves 3..7 (f4 >= 1536 = float 6144) are free.
  __shared__ float4 arena[4096];
  float* Msf = reinterpret_cast<float*>(arena);
  float* Wf  = reinterpret_cast<float*>(arena) + 576;

  const int t    = threadIdx.x;
  const int lane = t & 63;
  const int wv   = t >> 6;
  const int swz  = lane & 7;
  float4* __restrict__ R = arena + (wv << 9);

  float b0[NS], b1[NS], b2[NS], a1[NS], a2[NS];
  load_coefs(bc, ac, b0, b1, b2, a1, a2);

  const float4* __restrict__ gx_w = reinterpret_cast<const float4*>(x) +
      (size_t)blockIdx.x * (P * LQ) + ((size_t)wv << 10);
  float4* __restrict__ gy_w = reinterpret_cast<float4*>(out) +
      (size_t)blockIdx.x * (P * LQ) + ((size_t)wv << 10);

  // ---- P1 HT0 staging (HBM latency hides under Ms squarings) ----
  stage_ht(gx_w, R, lane, 0);

  // ---- Ms squarings in-register (wave 0 only), stored AFTER P1 barrier ----
  float mpow[9];
#pragma unroll
  for (int i = 0; i < 9; ++i) mpow[i] = 0.0f;
  if (t < 64) {
    const int r = lane >> 3, c = lane & 7;
    float p1[NS] = {0.f, 0.f, 0.f, 0.f};
    float p2[NS] = {0.f, 0.f, 0.f, 0.f};
    if (c & 1) p2[c >> 1] = 1.0f; else p1[c >> 1] = 1.0f;
    (void)step_cascade(0.0f, CO, p1, p2);
    float m = (r & 1) ? p2[r >> 1] : p1[r >> 1];  // A element (r,c)
#pragma unroll
    for (int it = 0; it < NSQ; ++it) {
      float acc = 0.0f;
#pragma unroll
      for (int k = 0; k < NSTATE; ++k)
        acc = fmaf(__shfl(m, r * 8 + k), __shfl(m, k * 8 + c), acc);
      m = acc;
      if (it >= LOG2L - 1) mpow[it - (LOG2L - 1)] = m;
    }
  }

  // ---- P1: compute chunk state from zero, half-tile at a time ----
  float s1[NS] = {0.f, 0.f, 0.f, 0.f};
  float s2[NS] = {0.f, 0.f, 0.f, 0.f};
  WAIT_VM0;
#pragma unroll
  for (int q = 0; q < 8; ++q) adv4(R[lane * 8 + (q ^ swz)], CO, s1, s2);
  WAIT_LGKM0;  // WAR: ds_reads done before HT1 overwrites the region
  stage_ht(gx_w, R, lane, 1);
  WAIT_VM0;
#pragma unroll
  for (int q = 0; q < 8; ++q) adv4(R[lane * 8 + (q ^ swz)], CO, s1, s2);

  float w[NSTATE];
#pragma unroll
  for (int k = 0; k < NS; ++k) { w[2 * k] = s1[k]; w[2 * k + 1] = s2[k]; }

  __syncthreads();  // #1: all P1 LDS traffic done; arena repurposed
  if (t < 64) {
#pragma unroll
    for (int d = 0; d < LOG2P; ++d) Msf[d * 64 + t] = mpow[d];
  }
  // waves 3..7: regions disjoint from Msf/Wf -> prefetch P4 HT0 now;
  // the shfl-scan below covers part of the load latency.
  if (wv >= 3) stage_ht(gx_w, R, lane, 0);
  __syncthreads();  // #2: Msf visible to all waves

  // ---- scan levels 0..5: in-wave Kogge-Stone via __shfl (no barriers) ----
#pragma unroll
  for (int d = 0; d < 6; ++d) {
    const int off = 1 << d;
    const int src = (lane >= off) ? (lane - off) : lane;
    float prev[NSTATE];
#pragma unroll
    for (int r = 0; r < NSTATE; ++r) prev[r] = __shfl(w[r], src);
    if (lane >= off) {
#pragma unroll
      for (int r = 0; r < NSTATE; ++r) {
        float acc = w[r];
#pragma unroll
        for (int k = 0; k < NSTATE; ++k)
          acc = fmaf(Msf[d * 64 + r * 8 + k], prev[k], acc);  // broadcast
        w[r] = acc;
      }
    }
  }

  // ---- scan levels 6..8: Wf-exchange (R13 verbatim) ----
  for (int d = 6; d < LOG2P; ++d) {
#pragma unroll
    for (int r = 0; r < NSTATE; ++r) Wf[t * 9 + r] = w[r];
    __syncthreads();
    if (t >= (1 << d)) {
      const int src = (t - (1 << d)) * 9;
      float prev[NSTATE];
#pragma unroll
      for (int r = 0; r < NSTATE; ++r) prev[r] = Wf[src + r];
#pragma unroll
      for (int r = 0; r < NSTATE; ++r) {
        float acc = w[r];
#pragma unroll
        for (int k = 0; k < NSTATE; ++k)
          acc = fmaf(Msf[d * 64 + r * 8 + k], prev[k], acc);  // broadcast
        w[r] = acc;
      }
    }
    __syncthreads();
  }

  // ---- exclusive shift -> s_init in registers (R13 verbatim) ----
#pragma unroll
  for (int r = 0; r < NSTATE; ++r) Wf[t * 9 + r] = w[r];
  __syncthreads();
  {
    const int src = (t == 0 ? 0 : t - 1) * 9;
#pragma unroll
    for (int k = 0; k < NS; ++k) {
      s1[k] = (t == 0) ? 0.0f : Wf[src + 2 * k];
      s2[k] = (t == 0) ? 0.0f : Wf[src + 2 * k + 1];
    }
  }
  __syncthreads();  // scan reads done before P4 staging overwrites arena

  // ---- P4: replay from exact init (R13 strict sequence; HT0 hoisted) ----
  if (wv < 3) stage_ht(gx_w, R, lane, 0);  // 3..7 already staged pre-scan
#pragma unroll
  for (int ht = 0; ht < 2; ++ht) {
    if (ht == 1) stage_ht(gx_w, R, lane, 1);
    WAIT_VM0;
#pragma unroll
    for (int q = 0; q < 8; ++q) {
      const int s = lane * 8 + (q ^ swz);
      R[s] = out4(R[s], CO, s1, s2);  // in-place: own slots only
    }
    WAIT_LGKM0;  // in-place writes committed before transpose-out reads
#pragma unroll
    for (int j = 0; j < 8; ++j) {
      const int cc = j * 8 + (lane >> 3);
      const int qq = lane & 7;
      const float4 v = R[j * 64 + lane];
      gy_w[cc * 16 + ht * 8 + (qq ^ (cc & 7))] = v;  // dense 128B lines
    }
    if (ht == 0) WAIT_LGKM0;  // WAR: store-side ds_reads done before HT1 staging
  }
}

extern "C" void kernel_launch(void* const* d_in, const int* in_sizes, int n_in,
                              void* d_out, int out_size, void* d_ws, size_t ws_size,
                              hipStream_t stream) {
  const float* x  = (const float*)d_in[0];  // (B, T, 1)
  const float* bc = (const float*)d_in[1];  // (NS, 3)
  const float* ac = (const float*)d_in[2];  // (NS, 2)
  float* out = (float*)d_out;               // (B, T, 1)

  k_fused<<<BATCH, P, 0, stream>>>(x, bc, ac, out);
}